// Round 2
// baseline (473.351 us; speedup 1.0000x reference)
//
#include <hip/hip_runtime.h>
#include <hip/hip_bf16.h>

// Problem: B=4, T=1024, C=1024, H=16, D=64. ALiBi encoder attention.
// Outputs: y [B,T,C] (4,194,304 fp32) then attn [B,H,T,T] (67,108,864 fp32).

typedef _Float16 half8 __attribute__((ext_vector_type(8)));
typedef _Float16 half4 __attribute__((ext_vector_type(4)));
typedef float f32x4 __attribute__((ext_vector_type(4)));

#define MFMA16(a, b, c) __builtin_amdgcn_mfma_f32_16x16x32_f16((a), (b), (c), 0, 0, 0)

// ---------------------------------------------------------------- convert ---
// Single launch converting x + all 4 weight matrices (saves 4 launch slots).
__global__ __launch_bounds__(256) void cvt_all(
    const float* __restrict__ x, const float* __restrict__ wq,
    const float* __restrict__ wk, const float* __restrict__ wv,
    const float* __restrict__ wp, _Float16* __restrict__ x16,
    _Float16* __restrict__ wq16, _Float16* __restrict__ wk16,
    _Float16* __restrict__ wv16, _Float16* __restrict__ wp16) {
  int i = blockIdx.x * 256 + threadIdx.x;  // float4 index; total 2,097,152
  const float* src;
  _Float16* dst;
  int off;
  if (i < 1048576) {
    src = x; dst = x16; off = i;
  } else {
    int j = i - 1048576;
    int sel = j >> 18;          // 262144 float4 per weight
    off = j & 262143;
    src = (sel == 0) ? wq : (sel == 1) ? wk : (sel == 2) ? wv : wp;
    dst = (sel == 0) ? wq16 : (sel == 1) ? wk16 : (sel == 2) ? wv16 : wp16;
  }
  float4 v = ((const float4*)src)[off];
  half4 o = {(_Float16)v.x, (_Float16)v.y, (_Float16)v.z, (_Float16)v.w};
  *(half4*)&dst[(size_t)off * 4] = o;
}

// ------------------------------------------------------------- gemm core ----
// m97-class structure: 128x128 tile, BK=64, 256 threads (4 waves in 2x2),
// 16x16x32 f16 MFMA, 16B global_load_lds staging, 2 barriers per 64-K step.
// XOR-8 swizzle on 16B k-chunks -> 2-way residual bank aliasing (free).
__device__ __forceinline__ void stage_tile(const _Float16* gbase, _Float16* lds, int tid) {
#pragma unroll
  for (int i = 0; i < 4; ++i) {
    int cid = i * 256 + tid;            // 0..1023 16B chunks (128 rows x 8)
    int row = cid >> 3, jl = cid & 7;
    int jg = jl ^ (row & 7);            // global chunk placed at lds chunk jl
    const _Float16* gp = gbase + (size_t)row * 1024 + jg * 8;
    _Float16* lp = lds + (size_t)cid * 8;  // linear: uniform base + lane*16B
    __builtin_amdgcn_global_load_lds(
        (const __attribute__((address_space(1))) unsigned int*)gp,
        (__attribute__((address_space(3))) unsigned int*)lp, 16, 0, 0);
  }
}

__device__ __forceinline__ void gemm_core(const _Float16* __restrict__ A,
                                          const _Float16* __restrict__ B,
                                          int m0, int n0, int tid,
                                          f32x4 (&acc)[4][4]) {
  __shared__ _Float16 As[128 * 64];
  __shared__ _Float16 Bs[128 * 64];
  const int wave = tid >> 6, lane = tid & 63;
  const int wr = wave >> 1, wc = wave & 1;
  const int lg = lane >> 4, lm = lane & 15;

  f32x4 z4 = {0.f, 0.f, 0.f, 0.f};
#pragma unroll
  for (int mt = 0; mt < 4; ++mt)
#pragma unroll
    for (int nt = 0; nt < 4; ++nt) acc[mt][nt] = z4;

  for (int kb = 0; kb < 16; ++kb) {
    stage_tile(A + (size_t)m0 * 1024 + kb * 64, As, tid);
    stage_tile(B + (size_t)n0 * 1024 + kb * 64, Bs, tid);
    __syncthreads();
#pragma unroll
    for (int h = 0; h < 2; ++h) {       // two K=32 halves of the 64-K tile
      half8 af[4], bf[4];
#pragma unroll
      for (int mt = 0; mt < 4; ++mt) {
        int row = wr * 64 + mt * 16 + lm;
        int ch = (lg + h * 4) ^ (row & 7);
        af[mt] = *(half8*)&As[row * 64 + ch * 8];
      }
#pragma unroll
      for (int nt = 0; nt < 4; ++nt) {
        int row = wc * 64 + nt * 16 + lm;
        int ch = (lg + h * 4) ^ (row & 7);
        bf[nt] = *(half8*)&Bs[row * 64 + ch * 8];
      }
#pragma unroll
      for (int mt = 0; mt < 4; ++mt)
#pragma unroll
        for (int nt = 0; nt < 4; ++nt)
          acc[mt][nt] = MFMA16(af[mt], bf[nt], acc[mt][nt]);
    }
    __syncthreads();
  }
}

// ------------------------------------------------------------- QKV GEMM -----
// z=0: Q = (0.125*log2e) * x@Wq^T -> [B,H,T,D]  (log2e folded so attn's
//      exp2 needs no extra multiply); z=1: K -> [B,H,T,D]; z=2: V -> [B,H,D,T]
__global__ __launch_bounds__(256) void qkv_gemm(
    const _Float16* __restrict__ x16, const _Float16* __restrict__ wq,
    const _Float16* __restrict__ wk, const _Float16* __restrict__ wv,
    _Float16* __restrict__ qo, _Float16* __restrict__ ko, _Float16* __restrict__ vo) {
  const int tid = threadIdx.x;
  const int z = blockIdx.z;
  const _Float16* W = (z == 0) ? wq : (z == 1) ? wk : wv;
  const int m0 = blockIdx.y * 128, n0 = blockIdx.x * 128;
  const int wave = tid >> 6, lane = tid & 63;
  const int wr = wave >> 1, wc = wave & 1;
  const int lg = lane >> 4, lm = lane & 15;

  f32x4 acc[4][4];
  gemm_core(x16, W, m0, n0, tid, acc);

  if (z == 2) {
#pragma unroll
    for (int mt = 0; mt < 4; ++mt) {
      int mbase = m0 + wr * 64 + mt * 16 + lg * 4;  // row = m (b,t)
      int b = mbase >> 10, t = mbase & 1023;
#pragma unroll
      for (int nt = 0; nt < 4; ++nt) {
        int n = n0 + wc * 64 + nt * 16 + lm;  // col = n (h,d)
        int h = n >> 6, d = n & 63;
        half4 o;
#pragma unroll
        for (int r = 0; r < 4; ++r) o[r] = (_Float16)acc[mt][nt][r];
        *(half4*)&vo[(((size_t)(b * 16 + h) * 64 + d) << 10) + t] = o;
      }
    }
  } else {
    _Float16* dst = (z == 0) ? qo : ko;
    // Q: fold 1/sqrt(64) AND log2(e) so softmax uses exp2 directly
    const float s = (z == 0) ? 0.18033688011112043f : 1.0f;
#pragma unroll
    for (int mt = 0; mt < 4; ++mt) {
      int mbase = m0 + wr * 64 + mt * 16 + lg * 4;
      int b = mbase >> 10, t = mbase & 1023;
#pragma unroll
      for (int nt = 0; nt < 4; ++nt) {
        int n = n0 + wc * 64 + nt * 16 + lm;
        int h = n >> 6, d = n & 63;
#pragma unroll
        for (int r = 0; r < 4; ++r)
          dst[((size_t)(b * 16 + h) * 1024 + t + r) * 64 + d] =
              (_Float16)(acc[mt][nt][r] * s);
      }
    }
  }
}

// ------------------------------------------------------------ attention -----
// grid (32 q-tiles, 64 bh), 512 threads = 8 waves (2 row-waves x 4 col-waves).
// Restructured vs r1: no max pass (inputs bounded, exp2 safe in fp32),
// normalization deferred past PV (PV consumes un-normalized P~, O scaled by
// inv at the end), attn stores moved AFTER PV so the 128 KB nontemporal
// store stream doesn't serialize against PV's V-loads via vmcnt.
// Barriers: 5 -> 3.
__global__ __launch_bounds__(512, 4) void attn_fused(
    const _Float16* __restrict__ qg, const _Float16* __restrict__ kg,
    const _Float16* __restrict__ vg, float* __restrict__ attn,
    _Float16* __restrict__ y16) {
  const int bh = blockIdx.y;
  const int b = bh >> 4, h = bh & 15;
  const int q0 = blockIdx.x << 5;
  const int tid = threadIdx.x;
  const int wave = tid >> 6, lane = tid & 63;
  const int wr = wave >> 2, wc = wave & 3;
  const int lg = lane >> 4, lm = lane & 15;

  __shared__ _Float16 q_lds[32 * 72];        // pad 64->72 (2-way max, free)
  __shared__ _Float16 p_lds[8 * 16 * 40];    // per-wave 16x32 P, pad 32->40
  __shared__ float red[4][32];               // cross-wave row-sum partials
  __shared__ float o_red[2][4][16 * 64];     // O partial reduction

  if (tid < 256) {
    int r = tid >> 3, c = tid & 7;
    *(half8*)&q_lds[r * 72 + c * 8] =
        *(const half8*)&qg[((size_t)bh * 1024 + q0 + r) * 64 + c * 8];
  }
  __syncthreads();

  f32x4 z4 = {0.f, 0.f, 0.f, 0.f};
  f32x4 acc[16];
#pragma unroll
  for (int i = 0; i < 16; ++i) acc[i] = z4;

  const int arow = wr * 16 + lm;
  half8 a0 = *(half8*)&q_lds[arow * 72 + lg * 8];
  half8 a1 = *(half8*)&q_lds[arow * 72 + 32 + lg * 8];
  const _Float16* kbase = kg + ((size_t)bh << 16);
#pragma unroll
  for (int nt = 0; nt < 16; ++nt) {
    int n = wc * 256 + nt * 16 + lm;
    half8 b0 = *(const half8*)&kbase[(size_t)n * 64 + lg * 8];
    half8 b1 = *(const half8*)&kbase[(size_t)n * 64 + 32 + lg * 8];
    acc[nt] = MFMA16(a0, b0, acc[nt]);
    acc[nt] = MFMA16(a1, b1, acc[nt]);
  }

  // Fused ALiBi + exp2 + row-sum, NO max subtraction.
  // acc already = S*log2(e) (log2e folded into Q scale). S is bounded
  // (~6 sigma ~ 6, ALiBi bias <= 0) so exp2 cannot overflow fp32; P~ <= ~400
  // fits f16 with same relative precision as normalized P.
  const float slope_l2 = exp2f(-0.5f * (float)(h + 1)) * 1.4426950408889634f;
  const int qrow0 = q0 + wr * 16 + lg * 4;
  float sm[4] = {0.f, 0.f, 0.f, 0.f};
#pragma unroll
  for (int nt = 0; nt < 16; ++nt) {
    int col = wc * 256 + nt * 16 + lm;
    float dbase = (float)(qrow0 - col);
#pragma unroll
    for (int r = 0; r < 4; ++r) {
      float p = exp2f(acc[nt][r] - slope_l2 * fabsf(dbase + (float)r));
      acc[nt][r] = p;   // un-normalized P~
      sm[r] += p;
    }
  }
#pragma unroll
  for (int r = 0; r < 4; ++r)
#pragma unroll
    for (int d = 1; d < 16; d <<= 1) sm[r] += __shfl_xor(sm[r], d, 64);
  if (lm == 0) {
#pragma unroll
    for (int r = 0; r < 4; ++r) red[wc][wr * 16 + lg * 4 + r] = sm[r];
  }
  // no barrier here: it migrates to after PV, hidden under MFMA work

  // PV with un-normalized P~: per 32-wide k-chunk, C-layout -> LDS ->
  // A-layout, V^T gives 16B b-frags.
  f32x4 oacc[4];
#pragma unroll
  for (int i = 0; i < 4; ++i) oacc[i] = z4;
  _Float16* pl = &p_lds[wave * 640];
  const _Float16* vbase = vg + ((size_t)bh << 16);
#pragma unroll
  for (int c = 0; c < 8; ++c) {
#pragma unroll
    for (int hv = 0; hv < 2; ++hv)
#pragma unroll
      for (int r = 0; r < 4; ++r)
        pl[(lg * 4 + r) * 40 + hv * 16 + lm] = (_Float16)acc[2 * c + hv][r];
    half8 pa = *(half8*)&pl[lm * 40 + lg * 8];
    int kk = wc * 256 + c * 32 + lg * 8;
#pragma unroll
    for (int dt = 0; dt < 4; ++dt) {
      half8 vb = *(const half8*)&vbase[(size_t)(dt * 16 + lm) * 1024 + kk];
      oacc[dt] = MFMA16(pa, vb, oacc[dt]);
    }
  }

  __syncthreads();  // red[] (row sums) now globally visible
  float inv[4];
#pragma unroll
  for (int r = 0; r < 4; ++r) {
    int row = wr * 16 + lg * 4 + r;
    inv[r] = 1.0f / (red[0][row] + red[1][row] + red[2][row] + red[3][row]);
  }

  // attn store (normalize on the fly), nontemporal; drains under epilogue.
  float* abase = attn + ((size_t)bh << 20);
#pragma unroll
  for (int nt = 0; nt < 16; ++nt) {
    int col = wc * 256 + nt * 16 + lm;
#pragma unroll
    for (int r = 0; r < 4; ++r)
      __builtin_nontemporal_store(acc[nt][r] * inv[r],
                                  &abase[((size_t)(qrow0 + r) << 10) + col]);
  }

  // cross-wave O reduction (4 col-waves per row-group), normalized by inv.
#pragma unroll
  for (int dt = 0; dt < 4; ++dt)
#pragma unroll
    for (int r = 0; r < 4; ++r)
      o_red[wr][wc][(lg * 4 + r) * 64 + dt * 16 + lm] = oacc[dt][r] * inv[r];
  __syncthreads();
#pragma unroll
  for (int it = 0; it < 4; ++it) {
    int idx = tid + it * 512;  // 32 rows x 64 cols
    int row = idx >> 6, col = idx & 63;
    int r2 = row & 15, wrr = row >> 4;
    float s = o_red[wrr][0][r2 * 64 + col] + o_red[wrr][1][r2 * 64 + col] +
              o_red[wrr][2][r2 * 64 + col] + o_red[wrr][3][r2 * 64 + col];
    y16[((size_t)(b * 1024 + q0 + row)) * 1024 + h * 64 + col] = (_Float16)s;
  }
}

// ------------------------------------------------------------- out proj -----
__global__ __launch_bounds__(256) void proj_gemm(const _Float16* __restrict__ y16,
                                                 const _Float16* __restrict__ wp,
                                                 float* __restrict__ out) {
  const int tid = threadIdx.x;
  const int m0 = blockIdx.y * 128, n0 = blockIdx.x * 128;
  const int wave = tid >> 6, lane = tid & 63;
  const int wr = wave >> 1, wc = wave & 1;
  const int lg = lane >> 4, lm = lane & 15;

  f32x4 acc[4][4];
  gemm_core(y16, wp, m0, n0, tid, acc);

#pragma unroll
  for (int mt = 0; mt < 4; ++mt) {
    int mbase = m0 + wr * 64 + mt * 16 + lg * 4;
#pragma unroll
    for (int nt = 0; nt < 4; ++nt) {
      int n = n0 + wc * 64 + nt * 16 + lm;
#pragma unroll
      for (int r = 0; r < 4; ++r)
        __builtin_nontemporal_store(acc[mt][nt][r],
                                    &out[(size_t)(mbase + r) * 1024 + n]);
    }
  }
}

// --------------------------------------------------------------- launch -----
extern "C" void kernel_launch(void* const* d_in, const int* in_sizes, int n_in,
                              void* d_out, int out_size, void* d_ws, size_t ws_size,
                              hipStream_t stream) {
  const float* x = (const float*)d_in[0];
  const float* Wq = (const float*)d_in[1];
  const float* Wk = (const float*)d_in[2];
  const float* Wv = (const float*)d_in[3];
  const float* Wp = (const float*)d_in[4];
  float* out = (float*)d_out;

  char* ws = (char*)d_ws;
  _Float16* x16 = (_Float16*)(ws);                    // 8 MB
  _Float16* wq16 = (_Float16*)(ws + (8u << 20));      // 2 MB
  _Float16* wk16 = (_Float16*)(ws + (10u << 20));     // 2 MB
  _Float16* wv16 = (_Float16*)(ws + (12u << 20));     // 2 MB
  _Float16* wp16 = (_Float16*)(ws + (14u << 20));     // 2 MB
  _Float16* q16 = (_Float16*)(ws + (16u << 20));      // 8 MB  [B,H,T,D]
  _Float16* k16 = (_Float16*)(ws + (24u << 20));      // 8 MB  [B,H,T,D]
  _Float16* v16 = (_Float16*)(ws + (32u << 20));      // 8 MB  [B,H,D,T]
  _Float16* y16 = (_Float16*)(ws + (40u << 20));      // 8 MB  [B,T,C]

  cvt_all<<<8192, 256, 0, stream>>>(x, Wq, Wk, Wv, Wp, x16, wq16, wk16, wv16, wp16);

  qkv_gemm<<<dim3(8, 32, 3), 256, 0, stream>>>(x16, wq16, wk16, wv16, q16, k16, v16);
  attn_fused<<<dim3(32, 64), 512, 0, stream>>>(q16, k16, v16, out + 4194304, y16);
  proj_gemm<<<dim3(8, 32, 1), 256, 0, stream>>>(y16, wp16, out);
}

// Round 3
// 468.057 us; speedup vs baseline: 1.0113x; 1.0113x over previous
//
#include <hip/hip_runtime.h>
#include <hip/hip_bf16.h>

// Problem: B=4, T=1024, C=1024, H=16, D=64. ALiBi encoder attention.
// Outputs: y [B,T,C] (4,194,304 fp32) then attn [B,H,T,T] (67,108,864 fp32).

typedef _Float16 half8 __attribute__((ext_vector_type(8)));
typedef _Float16 half4 __attribute__((ext_vector_type(4)));
typedef float f32x4 __attribute__((ext_vector_type(4)));

#define MFMA16(a, b, c) __builtin_amdgcn_mfma_f32_16x16x32_f16((a), (b), (c), 0, 0, 0)

// ---------------------------------------------------------------- convert ---
// Single launch converting x + all 4 weight matrices.
__global__ __launch_bounds__(256) void cvt_all(
    const float* __restrict__ x, const float* __restrict__ wq,
    const float* __restrict__ wk, const float* __restrict__ wv,
    const float* __restrict__ wp, _Float16* __restrict__ x16,
    _Float16* __restrict__ wq16, _Float16* __restrict__ wk16,
    _Float16* __restrict__ wv16, _Float16* __restrict__ wp16) {
  int i = blockIdx.x * 256 + threadIdx.x;  // float4 index; total 2,097,152
  const float* src;
  _Float16* dst;
  int off;
  if (i < 1048576) {
    src = x; dst = x16; off = i;
  } else {
    int j = i - 1048576;
    int sel = j >> 18;          // 262144 float4 per weight
    off = j & 262143;
    src = (sel == 0) ? wq : (sel == 1) ? wk : (sel == 2) ? wv : wp;
    dst = (sel == 0) ? wq16 : (sel == 1) ? wk16 : (sel == 2) ? wv16 : wp16;
  }
  float4 v = ((const float4*)src)[off];
  half4 o = {(_Float16)v.x, (_Float16)v.y, (_Float16)v.z, (_Float16)v.w};
  *(half4*)&dst[(size_t)off * 4] = o;
}

// ------------------------------------------------------------- gemm core ----
// m97-class structure: 128x128 tile, BK=64, 256 threads (4 waves in 2x2),
// 16x16x32 f16 MFMA, 16B global_load_lds staging, 2 barriers per 64-K step.
// XOR-8 swizzle on 16B k-chunks -> 2-way residual bank aliasing (free).
__device__ __forceinline__ void stage_tile(const _Float16* gbase, _Float16* lds, int tid) {
#pragma unroll
  for (int i = 0; i < 4; ++i) {
    int cid = i * 256 + tid;            // 0..1023 16B chunks (128 rows x 8)
    int row = cid >> 3, jl = cid & 7;
    int jg = jl ^ (row & 7);            // global chunk placed at lds chunk jl
    const _Float16* gp = gbase + (size_t)row * 1024 + jg * 8;
    _Float16* lp = lds + (size_t)cid * 8;  // linear: uniform base + lane*16B
    __builtin_amdgcn_global_load_lds(
        (const __attribute__((address_space(1))) unsigned int*)gp,
        (__attribute__((address_space(3))) unsigned int*)lp, 16, 0, 0);
  }
}

__device__ __forceinline__ void gemm_core(const _Float16* __restrict__ A,
                                          const _Float16* __restrict__ B,
                                          int m0, int n0, int tid,
                                          _Float16* As, _Float16* Bs,
                                          f32x4 (&acc)[4][4]) {
  const int wave = tid >> 6, lane = tid & 63;
  const int wr = wave >> 1, wc = wave & 1;
  const int lg = lane >> 4, lm = lane & 15;

  f32x4 z4 = {0.f, 0.f, 0.f, 0.f};
#pragma unroll
  for (int mt = 0; mt < 4; ++mt)
#pragma unroll
    for (int nt = 0; nt < 4; ++nt) acc[mt][nt] = z4;

  for (int kb = 0; kb < 16; ++kb) {
    stage_tile(A + (size_t)m0 * 1024 + kb * 64, As, tid);
    stage_tile(B + (size_t)n0 * 1024 + kb * 64, Bs, tid);
    __syncthreads();
#pragma unroll
    for (int h = 0; h < 2; ++h) {       // two K=32 halves of the 64-K tile
      half8 af[4], bf[4];
#pragma unroll
      for (int mt = 0; mt < 4; ++mt) {
        int row = wr * 64 + mt * 16 + lm;
        int ch = (lg + h * 4) ^ (row & 7);
        af[mt] = *(half8*)&As[row * 64 + ch * 8];
      }
#pragma unroll
      for (int nt = 0; nt < 4; ++nt) {
        int row = wc * 64 + nt * 16 + lm;
        int ch = (lg + h * 4) ^ (row & 7);
        bf[nt] = *(half8*)&Bs[row * 64 + ch * 8];
      }
#pragma unroll
      for (int mt = 0; mt < 4; ++mt)
#pragma unroll
        for (int nt = 0; nt < 4; ++nt)
          acc[mt][nt] = MFMA16(af[mt], bf[nt], acc[mt][nt]);
    }
    __syncthreads();
  }
}

// ------------------------------------------------------------- QKV GEMM -----
// z=0: Q = 0.125 * x@Wq^T -> [B,H,T,D]; z=1: K -> [B,H,T,D]; z=2: V -> [B,H,D,T]
// Epilogues go through an LDS transpose (pad 136 f16 = 272 B rows, 16B-aligned)
// so global stores are 16B coalesced instead of 2B/8B scatters. Cast points
// unchanged -> bit-identical output vs scalar-store version.
#define LDP 136

__global__ __launch_bounds__(256) void qkv_gemm(
    const _Float16* __restrict__ x16, const _Float16* __restrict__ wq,
    const _Float16* __restrict__ wk, const _Float16* __restrict__ wv,
    _Float16* __restrict__ qo, _Float16* __restrict__ ko, _Float16* __restrict__ vo) {
  const int tid = threadIdx.x;
  // XCD-aware bijective swizzle (768 blocks, 768%8==0): each XCD gets a
  // contiguous 96-block chunk -> A-panels (256 KB) reused within one L2.
  int flat = blockIdx.x + (blockIdx.y << 3) + (blockIdx.z << 8);
  int swz = (flat & 7) * 96 + (flat >> 3);
  const int z = swz >> 8;
  const int rem = swz & 255;
  const int m0 = (rem >> 3) * 128, n0 = (rem & 7) * 128;

  const _Float16* W = (z == 0) ? wq : (z == 1) ? wk : wv;
  const int wave = tid >> 6, lane = tid & 63;
  const int wr = wave >> 1, wc = wave & 1;
  const int lg = lane >> 4, lm = lane & 15;

  __shared__ _Float16 smem[128 * LDP];   // 34.8 KB; gemm uses first 32 KB
  _Float16* As = smem;
  _Float16* Bs = smem + 128 * 64;

  f32x4 acc[4][4];
  gemm_core(x16, W, m0, n0, tid, As, Bs, acc);
  // gemm_core ends with __syncthreads(): safe to reuse smem.

  const int bb = m0 >> 10, t0 = m0 & 1023, h0 = n0 >> 6;

  if (z == 2) {
    // transposed store into LDS: row = n_local (d), col = m_local (t);
    // r runs along t -> half4 ds_write.
#pragma unroll
    for (int mt = 0; mt < 4; ++mt)
#pragma unroll
      for (int nt = 0; nt < 4; ++nt) {
        half4 o;
#pragma unroll
        for (int r = 0; r < 4; ++r) o[r] = (_Float16)acc[mt][nt][r];
        *(half4*)&smem[(wc * 64 + nt * 16 + lm) * LDP + wr * 64 + mt * 16 + lg * 4] = o;
      }
    __syncthreads();
#pragma unroll
    for (int p = 0; p < 8; ++p) {
      int c2 = p * 256 + tid;            // 2048 chunks: 128 d-rows x 16 t-chunks
      int dl = c2 >> 4, t8 = c2 & 15;
      half8 v = *(half8*)&smem[dl * LDP + t8 * 8];
      int h = h0 + (dl >> 6), d = dl & 63;
      *(half8*)&vo[(((size_t)(bb * 16 + h) * 64 + d) << 10) + t0 + t8 * 8] = v;
    }
  } else {
    _Float16* dst = (z == 0) ? qo : ko;
    const float s = (z == 0) ? 0.125f : 1.0f;  // fold 1/sqrt(64) into Q
#pragma unroll
    for (int mt = 0; mt < 4; ++mt)
#pragma unroll
      for (int nt = 0; nt < 4; ++nt)
#pragma unroll
        for (int r = 0; r < 4; ++r)
          smem[(wr * 64 + mt * 16 + lg * 4 + r) * LDP + wc * 64 + nt * 16 + lm] =
              (_Float16)(acc[mt][nt][r] * s);
    __syncthreads();
#pragma unroll
    for (int p = 0; p < 8; ++p) {
      int c2 = p * 256 + tid;            // 2048 chunks: 128 t-rows x (2h x 8d8)
      int ml = c2 >> 4, hh = (c2 >> 3) & 1, d8 = c2 & 7;
      half8 v = *(half8*)&smem[ml * LDP + hh * 64 + d8 * 8];
      *(half8*)&dst[((size_t)(bb * 16 + h0 + hh) * 1024 + t0 + ml) * 64 + d8 * 8] = v;
    }
  }
}

// ------------------------------------------------------------ attention -----
// r1 structure restored (measured best): max-pass softmax, normalize + write
// attn BEFORE PV (store drain overlaps PV MFMA), 2 blocks/CU via
// __launch_bounds__(512,4). Added: XCD-aware swizzle so the 32 blocks sharing
// one bh's K/V (256 KB) run on the same XCD's L2.
__global__ __launch_bounds__(512, 4) void attn_fused(
    const _Float16* __restrict__ qg, const _Float16* __restrict__ kg,
    const _Float16* __restrict__ vg, float* __restrict__ attn,
    _Float16* __restrict__ y16) {
  int flat = blockIdx.x + (blockIdx.y << 5);           // 2048 blocks
  int swz = ((flat & 7) << 8) + (flat >> 3);           // bijective (2048%8==0)
  const int bh = swz >> 5;
  const int q0 = (swz & 31) << 5;
  const int b = bh >> 4, h = bh & 15;
  const int tid = threadIdx.x;
  const int wave = tid >> 6, lane = tid & 63;
  const int wr = wave >> 2, wc = wave & 3;
  const int lg = lane >> 4, lm = lane & 15;

  __shared__ _Float16 q_lds[32 * 72];        // pad 64->72 (2-way max, free)
  __shared__ _Float16 p_lds[8 * 16 * 40];    // per-wave 16x32 P, pad 32->40
  __shared__ float red[4][32];               // cross-wave softmax partials
  __shared__ float o_red[2][4][16 * 64];     // O partial reduction

  if (tid < 256) {
    int r = tid >> 3, c = tid & 7;
    *(half8*)&q_lds[r * 72 + c * 8] =
        *(const half8*)&qg[((size_t)bh * 1024 + q0 + r) * 64 + c * 8];
  }
  __syncthreads();

  f32x4 z4 = {0.f, 0.f, 0.f, 0.f};
  f32x4 acc[16];
#pragma unroll
  for (int i = 0; i < 16; ++i) acc[i] = z4;

  const int arow = wr * 16 + lm;
  half8 a0 = *(half8*)&q_lds[arow * 72 + lg * 8];
  half8 a1 = *(half8*)&q_lds[arow * 72 + 32 + lg * 8];
  const _Float16* kbase = kg + ((size_t)bh << 16);
#pragma unroll
  for (int nt = 0; nt < 16; ++nt) {
    int n = wc * 256 + nt * 16 + lm;
    half8 b0 = *(const half8*)&kbase[(size_t)n * 64 + lg * 8];
    half8 b1 = *(const half8*)&kbase[(size_t)n * 64 + 32 + lg * 8];
    acc[nt] = MFMA16(a0, b0, acc[nt]);
    acc[nt] = MFMA16(a1, b1, acc[nt]);
  }

  // ALiBi bias + row max (S layout: row=lg*4+r, col=lm per 16-tile)
  const float slope = exp2f(-0.5f * (float)(h + 1));
  const int qrow0 = q0 + wr * 16 + lg * 4;
  float mx[4] = {-1e30f, -1e30f, -1e30f, -1e30f};
#pragma unroll
  for (int nt = 0; nt < 16; ++nt) {
    int col = wc * 256 + nt * 16 + lm;
#pragma unroll
    for (int r = 0; r < 4; ++r) {
      float v = acc[nt][r] - slope * fabsf((float)(qrow0 + r - col));
      acc[nt][r] = v;
      mx[r] = fmaxf(mx[r], v);
    }
  }
#pragma unroll
  for (int r = 0; r < 4; ++r)
#pragma unroll
    for (int d = 1; d < 16; d <<= 1) mx[r] = fmaxf(mx[r], __shfl_xor(mx[r], d, 64));
  if (lm == 0) {
#pragma unroll
    for (int r = 0; r < 4; ++r) red[wc][wr * 16 + lg * 4 + r] = mx[r];
  }
  __syncthreads();
  float m[4];
#pragma unroll
  for (int r = 0; r < 4; ++r) {
    int row = wr * 16 + lg * 4 + r;
    m[r] = fmaxf(fmaxf(red[0][row], red[1][row]), fmaxf(red[2][row], red[3][row]));
  }
  __syncthreads();

  float sm[4] = {0.f, 0.f, 0.f, 0.f};
#pragma unroll
  for (int nt = 0; nt < 16; ++nt)
#pragma unroll
    for (int r = 0; r < 4; ++r) {
      float p = exp2f((acc[nt][r] - m[r]) * 1.4426950408889634f);
      acc[nt][r] = p;
      sm[r] += p;
    }
#pragma unroll
  for (int r = 0; r < 4; ++r)
#pragma unroll
    for (int d = 1; d < 16; d <<= 1) sm[r] += __shfl_xor(sm[r], d, 64);
  if (lm == 0) {
#pragma unroll
    for (int r = 0; r < 4; ++r) red[wc][wr * 16 + lg * 4 + r] = sm[r];
  }
  __syncthreads();
  float inv[4];
#pragma unroll
  for (int r = 0; r < 4; ++r) {
    int row = wr * 16 + lg * 4 + r;
    inv[r] = 1.0f / (red[0][row] + red[1][row] + red[2][row] + red[3][row]);
  }

  // normalize + write attn (fp32, write-once, nontemporal; drains under PV)
  float* abase = attn + ((size_t)bh << 20);
#pragma unroll
  for (int nt = 0; nt < 16; ++nt) {
    int col = wc * 256 + nt * 16 + lm;
#pragma unroll
    for (int r = 0; r < 4; ++r) {
      float pn = acc[nt][r] * inv[r];
      acc[nt][r] = pn;
      __builtin_nontemporal_store(pn, &abase[((size_t)(qrow0 + r) << 10) + col]);
    }
  }

  // PV: per 32-wide k-chunk, C-layout -> LDS -> A-layout, V^T gives 16B b-frags
  f32x4 oacc[4];
#pragma unroll
  for (int i = 0; i < 4; ++i) oacc[i] = z4;
  _Float16* pl = &p_lds[wave * 640];
  const _Float16* vbase = vg + ((size_t)bh << 16);
#pragma unroll
  for (int c = 0; c < 8; ++c) {
#pragma unroll
    for (int hv = 0; hv < 2; ++hv)
#pragma unroll
      for (int r = 0; r < 4; ++r)
        pl[(lg * 4 + r) * 40 + hv * 16 + lm] = (_Float16)acc[2 * c + hv][r];
    half8 pa = *(half8*)&pl[lm * 40 + lg * 8];
    int kk = wc * 256 + c * 32 + lg * 8;
#pragma unroll
    for (int dt = 0; dt < 4; ++dt) {
      half8 vb = *(const half8*)&vbase[(size_t)(dt * 16 + lm) * 1024 + kk];
      oacc[dt] = MFMA16(pa, vb, oacc[dt]);
    }
  }

  // cross-wave O reduction (4 col-waves per row-group)
#pragma unroll
  for (int dt = 0; dt < 4; ++dt)
#pragma unroll
    for (int r = 0; r < 4; ++r)
      o_red[wr][wc][(lg * 4 + r) * 64 + dt * 16 + lm] = oacc[dt][r];
  __syncthreads();
#pragma unroll
  for (int it = 0; it < 4; ++it) {
    int idx = tid + it * 512;  // 32 rows x 64 cols
    int row = idx >> 6, col = idx & 63;
    int r2 = row & 15, wrr = row >> 4;
    float s = o_red[wrr][0][r2 * 64 + col] + o_red[wrr][1][r2 * 64 + col] +
              o_red[wrr][2][r2 * 64 + col] + o_red[wrr][3][r2 * 64 + col];
    y16[((size_t)(b * 1024 + q0 + row)) * 1024 + h * 64 + col] = (_Float16)s;
  }
}

// ------------------------------------------------------------- out proj -----
__global__ __launch_bounds__(256) void proj_gemm(const _Float16* __restrict__ y16,
                                                 const _Float16* __restrict__ wp,
                                                 float* __restrict__ out) {
  const int tid = threadIdx.x;
  int flat = blockIdx.x + (blockIdx.y << 3);           // 256 blocks
  int swz = ((flat & 7) << 5) + (flat >> 3);           // bijective (256%8==0)
  const int m0 = (swz >> 3) * 128, n0 = (swz & 7) * 128;
  const int wave = tid >> 6, lane = tid & 63;
  const int wr = wave >> 1, wc = wave & 1;
  const int lg = lane >> 4, lm = lane & 15;

  __shared__ _Float16 smem[128 * 64 * 2];
  _Float16* As = smem;
  _Float16* Bs = smem + 128 * 64;

  f32x4 acc[4][4];
  gemm_core(y16, wp, m0, n0, tid, As, Bs, acc);

#pragma unroll
  for (int mt = 0; mt < 4; ++mt) {
    int mbase = m0 + wr * 64 + mt * 16 + lg * 4;
#pragma unroll
    for (int nt = 0; nt < 4; ++nt) {
      int n = n0 + wc * 64 + nt * 16 + lm;
#pragma unroll
      for (int r = 0; r < 4; ++r)
        __builtin_nontemporal_store(acc[mt][nt][r],
                                    &out[(size_t)(mbase + r) * 1024 + n]);
    }
  }
}

// --------------------------------------------------------------- launch -----
extern "C" void kernel_launch(void* const* d_in, const int* in_sizes, int n_in,
                              void* d_out, int out_size, void* d_ws, size_t ws_size,
                              hipStream_t stream) {
  const float* x = (const float*)d_in[0];
  const float* Wq = (const float*)d_in[1];
  const float* Wk = (const float*)d_in[2];
  const float* Wv = (const float*)d_in[3];
  const float* Wp = (const float*)d_in[4];
  float* out = (float*)d_out;

  char* ws = (char*)d_ws;
  _Float16* x16 = (_Float16*)(ws);                    // 8 MB
  _Float16* wq16 = (_Float16*)(ws + (8u << 20));      // 2 MB
  _Float16* wk16 = (_Float16*)(ws + (10u << 20));     // 2 MB
  _Float16* wv16 = (_Float16*)(ws + (12u << 20));     // 2 MB
  _Float16* wp16 = (_Float16*)(ws + (14u << 20));     // 2 MB
  _Float16* q16 = (_Float16*)(ws + (16u << 20));      // 8 MB  [B,H,T,D]
  _Float16* k16 = (_Float16*)(ws + (24u << 20));      // 8 MB  [B,H,T,D]
  _Float16* v16 = (_Float16*)(ws + (32u << 20));      // 8 MB  [B,H,D,T]
  _Float16* y16 = (_Float16*)(ws + (40u << 20));      // 8 MB  [B,T,C]

  cvt_all<<<8192, 256, 0, stream>>>(x, Wq, Wk, Wv, Wp, x16, wq16, wk16, wv16, wp16);

  qkv_gemm<<<dim3(8, 32, 3), 256, 0, stream>>>(x16, wq16, wk16, wv16, q16, k16, v16);
  attn_fused<<<dim3(32, 64), 512, 0, stream>>>(q16, k16, v16, out + 4194304, y16);
  proj_gemm<<<dim3(8, 32, 1), 256, 0, stream>>>(y16, wp16, out);
}